// Round 16
// baseline (117.445 us; speedup 1.0000x reference)
//
#include <hip/hip_runtime.h>
#include <hip/hip_bf16.h>

#define B_  4
#define S_  1024
#define D_  512
#define H_  8
#define DH_ 64
#define SCALE 0.044194173824159216f  // 1/sqrt(512)

typedef short bf16x8 __attribute__((ext_vector_type(8)));
typedef float f32x4  __attribute__((ext_vector_type(4)));

__device__ __forceinline__ unsigned short f2bf(float x) {
    union { __hip_bfloat16 h; unsigned short u; } cv;
    cv.h = __float2bfloat16(x);
    return cv.u;
}
__device__ __forceinline__ float bf2f(unsigned short h) {
    union { unsigned int u; float f; } v; v.u = ((unsigned int)h) << 16;
    return v.f;
}

// ===========================================================================
// Weight transpose + bf16 convert via LDS tile: T[o,i] = bf16(W[i,o])
// ===========================================================================
__global__ __launch_bounds__(256) void convert_wt_k(
    const float* __restrict__ W0, const float* __restrict__ W1,
    const float* __restrict__ W2, const float* __restrict__ W3,
    const float* __restrict__ W4,
    unsigned short* __restrict__ T0, unsigned short* __restrict__ T1,
    unsigned short* __restrict__ T2, unsigned short* __restrict__ T3,
    unsigned short* __restrict__ T4)
{
    __shared__ float tile[64][65];
    const float* W;
    unsigned short* T;
    switch (blockIdx.z) {
        case 0: W = W0; T = T0; break;
        case 1: W = W1; T = T1; break;
        case 2: W = W2; T = T2; break;
        case 3: W = W3; T = T3; break;
        default: W = W4; T = T4; break;
    }
    const int r0 = blockIdx.y * 64, c0 = blockIdx.x * 64;
    const int tx = threadIdx.x & 63, ty = threadIdx.x >> 6;   // ty: 0..3
#pragma unroll
    for (int it = 0; it < 16; ++it)
        tile[ty + 4 * it][tx] = W[(size_t)(r0 + ty + 4 * it) * 512 + c0 + tx];
    __syncthreads();
#pragma unroll
    for (int it = 0; it < 16; ++it)
        T[(size_t)(c0 + ty + 4 * it) * 512 + r0 + tx] = f2bf(tile[tx][ty + 4 * it]);
}

// ===========================================================================
// All four input projections, 128x128 tile, 512 thr. blockIdx.z = mode.
// mode 0: q -> qu/qv  [B,H,S,DH]
// mode 1: k -> kbf    BLOCKED fragment-order: per bh (65536 shorts):
//         flat = ((jc*2+kk)*8 + w)*512 + (lhi*16 + l15)*8 + ds
//         where t = jc*128 + 16w + l15, d = kk*32 + lhi*8 + ds.
//         Score's coalesced 16B/lane load then IS the MFMA B-fragment.
// mode 2: p -> pbf    same blocked layout
// mode 3: v -> v2     blocked [BH][tb=s>>5][d][s&31]  (PV B-operand)
// ===========================================================================
__global__ __launch_bounds__(512) void proj_all_k(
    const float* __restrict__ Aq_, const float* __restrict__ Ak_,
    const float* __restrict__ Ap_, const float* __restrict__ Av_,
    const unsigned short* __restrict__ WqT, const unsigned short* __restrict__ WkT,
    const unsigned short* __restrict__ WpT, const unsigned short* __restrict__ WvT,
    const float* __restrict__ bq, const float* __restrict__ bk,
    const float* __restrict__ bv,
    const float* __restrict__ ub, const float* __restrict__ vb,
    unsigned short* __restrict__ qu, unsigned short* __restrict__ qv,
    unsigned short* __restrict__ kbf, unsigned short* __restrict__ pbf,
    unsigned short* __restrict__ v2)
{
    __shared__ unsigned short Ab[128][72];
    __shared__ unsigned short Bb[128][72];
    const int mode = blockIdx.z;
    const float* A;
    const unsigned short* BT;
    switch (mode) {
        case 0: A = Aq_; BT = WqT; break;
        case 1: A = Ak_; BT = WkT; break;
        case 2: A = Ap_; BT = WpT; break;
        default: A = Av_; BT = WvT; break;
    }
    const int tid = threadIdx.x;
    const int i0 = blockIdx.x * 128, j0 = blockIdx.y * 128;
    const int w = tid >> 6, lane = tid & 63, l15 = lane & 15, lhi = lane >> 4;
    const int mr0 = (w >> 1) * 32, nc0 = (w & 1) * 64;
    f32x4 acc[2][4] = {};

    for (int k0 = 0; k0 < 512; k0 += 64) {
        __syncthreads();
#pragma unroll
        for (int it = 0; it < 4; ++it) {            // A: 128x64 fp32 -> bf16
            const int s = tid + it * 512;           // 2048 float4 slots
            const int row = s >> 4, f4 = (s & 15) * 4;
            float4 va = *(const float4*)&A[(size_t)(i0 + row) * 512 + k0 + f4];
            ushort4 hh;
            hh.x = f2bf(va.x); hh.y = f2bf(va.y); hh.z = f2bf(va.z); hh.w = f2bf(va.w);
            *(ushort4*)&Ab[row][f4] = hh;
        }
#pragma unroll
        for (int it = 0; it < 2; ++it) {            // B: 128x64 bf16, 16B slots
            const int s = tid + it * 512;
            const int row = s >> 3, g = (s & 7) * 8;
            *(bf16x8*)&Bb[row][g] = *(const bf16x8*)&BT[(size_t)(j0 + row) * 512 + k0 + g];
        }
        __syncthreads();
#pragma unroll
        for (int kk = 0; kk < 2; ++kk) {
            bf16x8 a0 = *(const bf16x8*)&Ab[mr0 + l15][kk * 32 + lhi * 8];
            bf16x8 a1 = *(const bf16x8*)&Ab[mr0 + 16 + l15][kk * 32 + lhi * 8];
#pragma unroll
            for (int n = 0; n < 4; ++n) {
                bf16x8 bn = *(const bf16x8*)&Bb[nc0 + 16 * n + l15][kk * 32 + lhi * 8];
                acc[0][n] = __builtin_amdgcn_mfma_f32_16x16x32_bf16(a0, bn, acc[0][n], 0, 0, 0);
                acc[1][n] = __builtin_amdgcn_mfma_f32_16x16x32_bf16(a1, bn, acc[1][n], 0, 0, 0);
            }
        }
    }

#pragma unroll
    for (int m = 0; m < 2; ++m)
#pragma unroll
        for (int n = 0; n < 4; ++n)
#pragma unroll
            for (int r = 0; r < 4; ++r) {
                const int grow = i0 + mr0 + 16 * m + 4 * lhi + r;
                const int gcol = j0 + nc0 + 16 * n + l15;
                const int b = grow >> 10, s = grow & 1023;
                const int h = gcol >> 6, d = gcol & 63;
                const float v = acc[m][n][r];
                if (mode == 3) {
                    const size_t idx = (((size_t)(b * H_ + h) * 32 + (s >> 5)) * 64 + d) * 32 + (s & 31);
                    v2[idx] = f2bf(v + bv[gcol]);
                } else if (mode == 0) {
                    const size_t idx = (((size_t)b * H_ + h) * S_ + s) * DH_ + d;
                    const float base = v + bq[gcol];
                    qu[idx] = f2bf(base + ub[gcol]);
                    qv[idx] = f2bf(base + vb[gcol]);
                } else {
                    // blocked fragment-order layout for kbf/pbf
                    const int jc = s >> 7, wch = (s >> 4) & 7, l15o = s & 15;
                    const int kko = d >> 5, lhio = (d >> 3) & 3, dso = d & 7;
                    const size_t idx = (size_t)(b * H_ + h) * 65536
                        + (size_t)(((jc * 2 + kko) * 8 + wch) * 64 + lhio * 16 + l15o) * 8 + dso;
                    if (mode == 1) kbf[idx] = f2bf(v + bk[gcol]);
                    else           pbf[idx] = f2bf(v);
                }
            }
}

// ===========================================================================
// bf16 GEMM with fp32 output: C[4096,512] = A(bf16) @ BT^T (+bias)
// ===========================================================================
__global__ __launch_bounds__(256) void gemm_bf16_k(
    const unsigned short* __restrict__ A,   // [4096,512] bf16
    const unsigned short* __restrict__ BT,  // [512,512] bf16
    const float* __restrict__ bias,
    float* __restrict__ C)                  // [4096,512] fp32
{
    __shared__ unsigned short Ab[64][72];
    __shared__ unsigned short Bb[64][72];
    const int tid = threadIdx.x;
    const int i0 = blockIdx.x * 64, j0 = blockIdx.y * 64;
    const int w = tid >> 6, lane = tid & 63, l15 = lane & 15, lhi = lane >> 4;
    const int mr0 = (w >> 1) * 32, nc0 = (w & 1) * 32;
    f32x4 acc[2][2] = {};

    for (int k0 = 0; k0 < 512; k0 += 64) {
        __syncthreads();
#pragma unroll
        for (int it = 0; it < 2; ++it) {
            const int s = tid + it * 256;
            const int row = s >> 3, g = (s & 7) * 8;
            *(bf16x8*)&Ab[row][g] = *(const bf16x8*)&A[(size_t)(i0 + row) * 512 + k0 + g];
            *(bf16x8*)&Bb[row][g] = *(const bf16x8*)&BT[(size_t)(j0 + row) * 512 + k0 + g];
        }
        __syncthreads();
#pragma unroll
        for (int kk = 0; kk < 2; ++kk) {
            bf16x8 a0 = *(const bf16x8*)&Ab[mr0 + l15][kk * 32 + lhi * 8];
            bf16x8 a1 = *(const bf16x8*)&Ab[mr0 + 16 + l15][kk * 32 + lhi * 8];
            bf16x8 b0 = *(const bf16x8*)&Bb[nc0 + l15][kk * 32 + lhi * 8];
            bf16x8 b1 = *(const bf16x8*)&Bb[nc0 + 16 + l15][kk * 32 + lhi * 8];
            acc[0][0] = __builtin_amdgcn_mfma_f32_16x16x32_bf16(a0, b0, acc[0][0], 0, 0, 0);
            acc[0][1] = __builtin_amdgcn_mfma_f32_16x16x32_bf16(a0, b1, acc[0][1], 0, 0, 0);
            acc[1][0] = __builtin_amdgcn_mfma_f32_16x16x32_bf16(a1, b0, acc[1][0], 0, 0, 0);
            acc[1][1] = __builtin_amdgcn_mfma_f32_16x16x32_bf16(a1, b1, acc[1][1], 0, 0, 0);
        }
    }

#pragma unroll
    for (int m = 0; m < 2; ++m)
#pragma unroll
        for (int n = 0; n < 2; ++n)
#pragma unroll
            for (int r = 0; r < 4; ++r) {
                const int grow = i0 + mr0 + 16 * m + 4 * lhi + r;
                const int gcol = j0 + nc0 + 16 * n + l15;
                C[(size_t)grow * 512 + gcol] = acc[m][n][r] + bias[gcol];
            }
}

// ===========================================================================
// Fused score + softmax + PV, QBLK=16 rows/block.
// Main loop: ZERO LDS staging — K/P are pre-blocked in fragment order, so a
// coalesced 16B/lane global load (4 cache lines/instr, same pattern as the
// old staging loads) IS the MFMA B-fragment. No barriers, no lane shuffle.
// (R7/R9's direct loads failed because frag-layout loads from [S][DH] were
// 16-line scattered; the producer-side re-layout fixes that.)
// LDS: Rsh 33KB + red + fred = ~37.7KB. launch_bounds(512,4): VGPR cap 128.
// R is stored PRE-SHIFTED (scatter): R[gr,u] -> Rsh[rl][u+gr-1023] if
// u>=1023-gr, else Rsh[rl-1][u+gr+1]; slot j=i+1 pre-zeroed.
// T14: first-half V loads issued before the softmax epilogue.
// ===========================================================================
#define RS 1032   // padded LDS row stride (shorts)
#define QBLK 16

__global__ __launch_bounds__(512, 4) void score_fused_k(
    const unsigned short* __restrict__ qu_g,  // [B,H,S,DH]
    const unsigned short* __restrict__ qv_g,
    const unsigned short* __restrict__ kb_g,  // blocked fragment-order
    const unsigned short* __restrict__ pb_g,  // blocked fragment-order
    const unsigned short* __restrict__ v2_g,  // blocked [BH][32][64][32]
    float* __restrict__ attn,                 // [B,H,S,S]
    unsigned short* __restrict__ ctx_g)       // [B,S,D] bf16
{
    __shared__ unsigned short Rsh[16 * RS];   // shifted R, then P  (33 KB)
    __shared__ float red[16][9];
    __shared__ float fred[1024];              // 4 KB PV partials

    const int tid = threadIdx.x;
    const int i0 = blockIdx.x * QBLK;
    const int bh = blockIdx.y;
    const int w = tid >> 6, lane = tid & 63, l15 = lane & 15, lhi = lane >> 4;

    const unsigned short* qu_b = qu_g + (size_t)bh * S_ * DH_;
    const unsigned short* qv_b = qv_g + (size_t)bh * S_ * DH_;
    const unsigned short* kb_b = kb_g + (size_t)bh * 65536;
    const unsigned short* pb_b = pb_g + (size_t)bh * 65536;

    // ---- zero the j = i+1 slots of Rsh (one per row) ----
    if (tid < 16) {
        const int j = i0 + tid + 1;
        if (j <= 1023) Rsh[tid * RS + j] = 0;
    }

    // ---- A-operand fragments in registers ----
    bf16x8 qf[2], aq0[2], aq1[2];
    {
        const int qrow  = i0 + l15;
        const int qrow1 = min(i0 + 16 + l15, S_ - 1);
#pragma unroll
        for (int kk = 0; kk < 2; ++kk) {
            const int off = kk * 32 + lhi * 8;
            qf[kk]  = *(const bf16x8*)&qu_b[(size_t)qrow  * DH_ + off];
            aq0[kk] = *(const bf16x8*)&qv_b[(size_t)qrow  * DH_ + off];
            aq1[kk] = *(const bf16x8*)&qv_b[(size_t)qrow1 * DH_ + off];
        }
    }

    // ---- main loop: 8 chunks; direct fragment loads, 6 MFMA each ----
    const size_t lbase = (size_t)w * 512 + (size_t)lane * 8;
    f32x4 acc[8] = {};
#pragma unroll
    for (int jc = 0; jc < 8; ++jc) {
        const size_t cb = (size_t)jc * 8192 + lbase;   // ((jc*2+0)*8+w)*512 + lane*8
        bf16x8 kf0 = *(const bf16x8*)&kb_b[cb];
        bf16x8 kf1 = *(const bf16x8*)&kb_b[cb + 4096]; // kk=1
        bf16x8 pf0 = *(const bf16x8*)&pb_b[cb];
        bf16x8 pf1 = *(const bf16x8*)&pb_b[cb + 4096];

        acc[jc] = __builtin_amdgcn_mfma_f32_16x16x32_bf16(qf[0], kf0, acc[jc], 0, 0, 0);
        acc[jc] = __builtin_amdgcn_mfma_f32_16x16x32_bf16(qf[1], kf1, acc[jc], 0, 0, 0);
        f32x4 racc0 = {}, racc1 = {};
        racc0 = __builtin_amdgcn_mfma_f32_16x16x32_bf16(aq0[0], pf0, racc0, 0, 0, 0);
        racc0 = __builtin_amdgcn_mfma_f32_16x16x32_bf16(aq0[1], pf1, racc0, 0, 0, 0);
        racc1 = __builtin_amdgcn_mfma_f32_16x16x32_bf16(aq1[0], pf0, racc1, 0, 0, 0);
        racc1 = __builtin_amdgcn_mfma_f32_16x16x32_bf16(aq1[1], pf1, racc1, 0, 0, 0);

        // -- scatter-store R pre-shifted --
        const int u = jc * 128 + 16 * w + l15;
#pragma unroll
        for (int r = 0; r < 4; ++r) {
            const int rl = 4 * lhi + r;          // R local row 0..15
            const int gr = i0 + rl;
            const int jlo = u + gr - 1023;
            const unsigned short val = f2bf(racc0[r]);
            if (jlo >= 0)      Rsh[rl * RS + jlo] = val;
            else if (rl >= 1)  Rsh[(rl - 1) * RS + (u + gr + 1)] = val;
            // rl==0 && jlo<0: previous strip's territory -> drop
        }
        if (lhi == 0) {                          // R local row 16 (racc1[0])
            const int jhi = u + i0 + 17;
            if (jhi <= 1023) Rsh[15 * RS + jhi] = f2bf(racc1[0]);
        }
    }
    __syncthreads();                       // Rsh (shifted R) complete

    // ---- T14: issue first-half V loads now; latency hides under softmax ----
    const int b4 = bh >> 3, h4 = bh & 7;
    const int nblk = w & 3;                // d-block (16 cols)
    const int kh = w >> 2;                 // K-half (512 each)
    const unsigned short* v2b = v2_g + (size_t)bh * 32 * 2048;
    const int dd = 16 * nblk + l15;
    bf16x8 bbufA[8];
#pragma unroll
    for (int ki = 0; ki < 8; ++ki) {
        const int tb = kh * 16 + ki;
        bbufA[ki] = *(const bf16x8*)&v2b[(size_t)tb * 2048 + dd * 32 + lhi * 8];
    }

    // ---- epilogue: branch-free pos add + scale + softmax ----
    const int il = 4 * lhi;                // + r
    float rmax[4], rsum[4];
#pragma unroll
    for (int r = 0; r < 4; ++r) rmax[r] = -3.0e38f;

#pragma unroll
    for (int jc = 0; jc < 8; ++jc)
#pragma unroll
        for (int r = 0; r < 4; ++r) {
            const int row = il + r;
            const int j = jc * 128 + 16 * w + l15;
            const float pos = bf2f(Rsh[row * RS + j]);
            const float s = (acc[jc][r] + pos) * SCALE;
            acc[jc][r] = s;
            rmax[r] = fmaxf(rmax[r], s);
        }

#pragma unroll
    for (int r = 0; r < 4; ++r)
#pragma unroll
        for (int off = 1; off < 16; off <<= 1)
            rmax[r] = fmaxf(rmax[r], __shfl_xor(rmax[r], off));
    if (l15 == 0)
#pragma unroll
        for (int r = 0; r < 4; ++r) red[il + r][w] = rmax[r];
    __syncthreads();
#pragma unroll
    for (int r = 0; r < 4; ++r) {
        float mx = red[il + r][0];
#pragma unroll
        for (int ww = 1; ww < 8; ++ww) mx = fmaxf(mx, red[il + r][ww]);
        rmax[r] = mx;
        rsum[r] = 0.f;
    }
    __syncthreads();                       // red reads done before reuse

#pragma unroll
    for (int jc = 0; jc < 8; ++jc)
#pragma unroll
        for (int r = 0; r < 4; ++r) {
            const float e = __expf(acc[jc][r] - rmax[r]);
            acc[jc][r] = e;
            rsum[r] += e;
        }
#pragma unroll
    for (int r = 0; r < 4; ++r)
#pragma unroll
        for (int off = 1; off < 16; off <<= 1)
            rsum[r] += __shfl_xor(rsum[r], off);
    if (l15 == 0)
#pragma unroll
        for (int r = 0; r < 4; ++r) red[il + r][w] = rsum[r];
    __syncthreads();

    // ---- normalize: write attn (fp32) + P (bf16, overwrites Rsh) ----
    float* attn_b = attn + (size_t)bh * S_ * S_;
#pragma unroll
    for (int r = 0; r < 4; ++r) {
        float sum = red[il + r][0];
#pragma unroll
        for (int ww = 1; ww < 8; ++ww) sum += red[il + r][ww];
        const float inv = 1.f / sum;
#pragma unroll
        for (int jc = 0; jc < 8; ++jc) {
            const int j = jc * 128 + 16 * w + l15;
            const float pn = acc[jc][r] * inv;
            attn_b[(size_t)(i0 + il + r) * S_ + j] = pn;
            Rsh[(il + r) * RS + j] = f2bf(pn);
        }
    }
    __syncthreads();                       // P complete in LDS

    // ---- fused PV: ctx[i0..i0+16, h*64..] = P @ V ----
    bf16x8 bbufB[8];
#pragma unroll
    for (int ki = 0; ki < 8; ++ki) {
        const int tb = kh * 16 + 8 + ki;
        bbufB[ki] = *(const bf16x8*)&v2b[(size_t)tb * 2048 + dd * 32 + lhi * 8];
    }
    f32x4 cacc = {};
#pragma unroll
    for (int ki = 0; ki < 8; ++ki) {
        const int t0 = (kh * 16 + ki) * 32 + lhi * 8;
        bf16x8 a = *(const bf16x8*)&Rsh[l15 * RS + t0];
        cacc = __builtin_amdgcn_mfma_f32_16x16x32_bf16(a, bbufA[ki], cacc, 0, 0, 0);
    }
#pragma unroll
    for (int ki = 0; ki < 8; ++ki) {
        const int t0 = (kh * 16 + 8 + ki) * 32 + lhi * 8;
        bf16x8 a = *(const bf16x8*)&Rsh[l15 * RS + t0];
        cacc = __builtin_amdgcn_mfma_f32_16x16x32_bf16(a, bbufB[ki], cacc, 0, 0, 0);
    }
    if (kh == 0) {
#pragma unroll
        for (int r = 0; r < 4; ++r)
            fred[(nblk * 16 + 4 * lhi + r) * 16 + l15] = cacc[r];
    }
    __syncthreads();
    if (kh == 1) {
#pragma unroll
        for (int r = 0; r < 4; ++r) {
            const float vs = cacc[r] + fred[(nblk * 16 + 4 * lhi + r) * 16 + l15];
            const int srow = i0 + 4 * lhi + r;
            ctx_g[((size_t)(b4 * S_ + srow)) * D_ + h4 * DH_ + 16 * nblk + l15] = f2bf(vs);
        }
    }
}

// ===========================================================================
extern "C" void kernel_launch(void* const* d_in, const int* in_sizes, int n_in,
                              void* d_out, int out_size, void* d_ws, size_t ws_size,
                              hipStream_t stream)
{
    const float* query = (const float*)d_in[0];
    const float* key_  = (const float*)d_in[1];
    const float* value = (const float*)d_in[2];
    const float* pose  = (const float*)d_in[3];
    const float* Wq = (const float*)d_in[4];
    const float* bq = (const float*)d_in[5];
    const float* Wk = (const float*)d_in[6];
    const float* bk = (const float*)d_in[7];
    const float* Wv = (const float*)d_in[8];
    const float* bv = (const float*)d_in[9];
    const float* Wp = (const float*)d_in[10];
    const float* Wo = (const float*)d_in[11];
    const float* bo = (const float*)d_in[12];
    const float* u_bias = (const float*)d_in[13];
    const float* v_bias = (const float*)d_in[14];

    const size_t NTOK = (size_t)B_ * S_ * D_;   // 2,097,152
    float* out  = (float*)d_out;                // [B,S,D]
    float* attn = (float*)d_out + NTOK;         // [B,H,S,S]

    unsigned short* qu  = (unsigned short*)d_ws;
    unsigned short* qv  = qu + NTOK;
    unsigned short* kbf = qv + NTOK;
    unsigned short* pbf = kbf + NTOK;
    unsigned short* WqT = pbf + NTOK;
    unsigned short* WkT = WqT + 262144;
    unsigned short* WpT = WkT + 262144;
    unsigned short* WvT = WpT + 262144;
    unsigned short* WoT = WvT + 262144;
    unsigned short* v2  = WoT + 262144;         // blocked V bf16
    unsigned short* ctx = v2 + NTOK;            // [B,S,D] bf16

    const dim3 blk256(256);
    const dim3 gproj(64, 8);

    convert_wt_k<<<dim3(8, 8, 5), blk256, 0, stream>>>(Wq, Wk, Wp, Wv, Wo,
                                                       WqT, WkT, WpT, WvT, WoT);

    proj_all_k<<<dim3(32, 4, 4), dim3(512), 0, stream>>>(
        query, key_, pose, value,
        WqT, WkT, WpT, WvT,
        bq, bk, bv, u_bias, v_bias,
        qu, qv, kbf, pbf, v2);

    score_fused_k<<<dim3(S_ / QBLK, B_ * H_), dim3(512), 0, stream>>>(
        qu, qv, kbf, pbf, v2, attn, ctx);

    gemm_bf16_k<<<gproj, blk256, 0, stream>>>(ctx, WoT, bo, out);
}

// Round 17
// 113.281 us; speedup vs baseline: 1.0368x; 1.0368x over previous
//
#include <hip/hip_runtime.h>
#include <hip/hip_bf16.h>

#define B_  4
#define S_  1024
#define D_  512
#define H_  8
#define DH_ 64
#define SCALE 0.044194173824159216f  // 1/sqrt(512)

typedef short bf16x8 __attribute__((ext_vector_type(8)));
typedef float f32x4  __attribute__((ext_vector_type(4)));

// Native bf16 convert (RTNE): compiler emits v_cvt_pk_bf16_f32 and packs
// adjacent conversions.
__device__ __forceinline__ unsigned short f2bf(float x) {
    union { __hip_bfloat16 h; unsigned short u; } cv;
    cv.h = __float2bfloat16(x);
    return cv.u;
}
__device__ __forceinline__ float bf2f(unsigned short h) {
    union { unsigned int u; float f; } v; v.u = ((unsigned int)h) << 16;
    return v.f;
}

// ===========================================================================
// Weight transpose + bf16 convert via LDS tile: T[o,i] = bf16(W[i,o])
// ===========================================================================
__global__ __launch_bounds__(256) void convert_wt_k(
    const float* __restrict__ W0, const float* __restrict__ W1,
    const float* __restrict__ W2, const float* __restrict__ W3,
    const float* __restrict__ W4,
    unsigned short* __restrict__ T0, unsigned short* __restrict__ T1,
    unsigned short* __restrict__ T2, unsigned short* __restrict__ T3,
    unsigned short* __restrict__ T4)
{
    __shared__ float tile[64][65];
    const float* W;
    unsigned short* T;
    switch (blockIdx.z) {
        case 0: W = W0; T = T0; break;
        case 1: W = W1; T = T1; break;
        case 2: W = W2; T = T2; break;
        case 3: W = W3; T = T3; break;
        default: W = W4; T = T4; break;
    }
    const int r0 = blockIdx.y * 64, c0 = blockIdx.x * 64;
    const int tx = threadIdx.x & 63, ty = threadIdx.x >> 6;   // ty: 0..3
#pragma unroll
    for (int it = 0; it < 16; ++it)
        tile[ty + 4 * it][tx] = W[(size_t)(r0 + ty + 4 * it) * 512 + c0 + tx];
    __syncthreads();
#pragma unroll
    for (int it = 0; it < 16; ++it)
        T[(size_t)(c0 + ty + 4 * it) * 512 + r0 + tx] = f2bf(tile[tx][ty + 4 * it]);
}

// ===========================================================================
// All four input projections, 128x128 tile, 512 thr (8 waves = 4M x 2N,
// per-wave 32x64 output). blockIdx.z = mode.
// mode 0: q -> qu = bf16(acc+bq+u_bias), qv = bf16(acc+bq+v_bias)  [B,H,S,DH]
// mode 1: k -> bf16(acc+bk)  [B,H,S,DH]
// mode 2: p -> bf16(acc)     [B,H,S,DH]
// mode 3: v -> bf16(acc+bv)  blocked [BH][tb=s>>5][d][s&31]  (PV B-operand)
// ===========================================================================
__global__ __launch_bounds__(512) void proj_all_k(
    const float* __restrict__ Aq_, const float* __restrict__ Ak_,
    const float* __restrict__ Ap_, const float* __restrict__ Av_,
    const unsigned short* __restrict__ WqT, const unsigned short* __restrict__ WkT,
    const unsigned short* __restrict__ WpT, const unsigned short* __restrict__ WvT,
    const float* __restrict__ bq, const float* __restrict__ bk,
    const float* __restrict__ bv,
    const float* __restrict__ ub, const float* __restrict__ vb,
    unsigned short* __restrict__ qu, unsigned short* __restrict__ qv,
    unsigned short* __restrict__ kbf, unsigned short* __restrict__ pbf,
    unsigned short* __restrict__ v2)
{
    __shared__ unsigned short Ab[128][72];
    __shared__ unsigned short Bb[128][72];
    const int mode = blockIdx.z;
    const float* A;
    const unsigned short* BT;
    switch (mode) {
        case 0: A = Aq_; BT = WqT; break;
        case 1: A = Ak_; BT = WkT; break;
        case 2: A = Ap_; BT = WpT; break;
        default: A = Av_; BT = WvT; break;
    }
    const int tid = threadIdx.x;
    const int i0 = blockIdx.x * 128, j0 = blockIdx.y * 128;
    const int w = tid >> 6, lane = tid & 63, l15 = lane & 15, lhi = lane >> 4;
    const int mr0 = (w >> 1) * 32, nc0 = (w & 1) * 64;
    f32x4 acc[2][4] = {};

    for (int k0 = 0; k0 < 512; k0 += 64) {
        __syncthreads();
#pragma unroll
        for (int it = 0; it < 4; ++it) {            // A: 128x64 fp32 -> bf16
            const int s = tid + it * 512;           // 2048 float4 slots
            const int row = s >> 4, f4 = (s & 15) * 4;
            float4 va = *(const float4*)&A[(size_t)(i0 + row) * 512 + k0 + f4];
            ushort4 hh;
            hh.x = f2bf(va.x); hh.y = f2bf(va.y); hh.z = f2bf(va.z); hh.w = f2bf(va.w);
            *(ushort4*)&Ab[row][f4] = hh;
        }
#pragma unroll
        for (int it = 0; it < 2; ++it) {            // B: 128x64 bf16, 16B slots
            const int s = tid + it * 512;
            const int row = s >> 3, g = (s & 7) * 8;
            *(bf16x8*)&Bb[row][g] = *(const bf16x8*)&BT[(size_t)(j0 + row) * 512 + k0 + g];
        }
        __syncthreads();
#pragma unroll
        for (int kk = 0; kk < 2; ++kk) {
            bf16x8 a0 = *(const bf16x8*)&Ab[mr0 + l15][kk * 32 + lhi * 8];
            bf16x8 a1 = *(const bf16x8*)&Ab[mr0 + 16 + l15][kk * 32 + lhi * 8];
#pragma unroll
            for (int n = 0; n < 4; ++n) {
                bf16x8 bn = *(const bf16x8*)&Bb[nc0 + 16 * n + l15][kk * 32 + lhi * 8];
                acc[0][n] = __builtin_amdgcn_mfma_f32_16x16x32_bf16(a0, bn, acc[0][n], 0, 0, 0);
                acc[1][n] = __builtin_amdgcn_mfma_f32_16x16x32_bf16(a1, bn, acc[1][n], 0, 0, 0);
            }
        }
    }

#pragma unroll
    for (int m = 0; m < 2; ++m)
#pragma unroll
        for (int n = 0; n < 4; ++n)
#pragma unroll
            for (int r = 0; r < 4; ++r) {
                const int grow = i0 + mr0 + 16 * m + 4 * lhi + r;
                const int gcol = j0 + nc0 + 16 * n + l15;
                const int b = grow >> 10, s = grow & 1023;
                const int h = gcol >> 6, d = gcol & 63;
                const float v = acc[m][n][r];
                if (mode == 3) {
                    const size_t idx = (((size_t)(b * H_ + h) * 32 + (s >> 5)) * 64 + d) * 32 + (s & 31);
                    v2[idx] = f2bf(v + bv[gcol]);
                } else {
                    const size_t idx = (((size_t)b * H_ + h) * S_ + s) * DH_ + d;
                    if (mode == 0) {
                        const float base = v + bq[gcol];
                        qu[idx] = f2bf(base + ub[gcol]);
                        qv[idx] = f2bf(base + vb[gcol]);
                    } else if (mode == 1) {
                        kbf[idx] = f2bf(v + bk[gcol]);
                    } else {
                        pbf[idx] = f2bf(v);
                    }
                }
            }
}

// ===========================================================================
// bf16 GEMM with fp32 output: C[4096,512] = A(bf16) @ BT^T (+bias)
// ===========================================================================
__global__ __launch_bounds__(256) void gemm_bf16_k(
    const unsigned short* __restrict__ A,   // [4096,512] bf16
    const unsigned short* __restrict__ BT,  // [512,512] bf16
    const float* __restrict__ bias,
    float* __restrict__ C)                  // [4096,512] fp32
{
    __shared__ unsigned short Ab[64][72];
    __shared__ unsigned short Bb[64][72];
    const int tid = threadIdx.x;
    const int i0 = blockIdx.x * 64, j0 = blockIdx.y * 64;
    const int w = tid >> 6, lane = tid & 63, l15 = lane & 15, lhi = lane >> 4;
    const int mr0 = (w >> 1) * 32, nc0 = (w & 1) * 32;
    f32x4 acc[2][2] = {};

    for (int k0 = 0; k0 < 512; k0 += 64) {
        __syncthreads();
#pragma unroll
        for (int it = 0; it < 2; ++it) {
            const int s = tid + it * 256;
            const int row = s >> 3, g = (s & 7) * 8;
            *(bf16x8*)&Ab[row][g] = *(const bf16x8*)&A[(size_t)(i0 + row) * 512 + k0 + g];
            *(bf16x8*)&Bb[row][g] = *(const bf16x8*)&BT[(size_t)(j0 + row) * 512 + k0 + g];
        }
        __syncthreads();
#pragma unroll
        for (int kk = 0; kk < 2; ++kk) {
            bf16x8 a0 = *(const bf16x8*)&Ab[mr0 + l15][kk * 32 + lhi * 8];
            bf16x8 a1 = *(const bf16x8*)&Ab[mr0 + 16 + l15][kk * 32 + lhi * 8];
            bf16x8 b0 = *(const bf16x8*)&Bb[nc0 + l15][kk * 32 + lhi * 8];
            bf16x8 b1 = *(const bf16x8*)&Bb[nc0 + 16 + l15][kk * 32 + lhi * 8];
            acc[0][0] = __builtin_amdgcn_mfma_f32_16x16x32_bf16(a0, b0, acc[0][0], 0, 0, 0);
            acc[0][1] = __builtin_amdgcn_mfma_f32_16x16x32_bf16(a0, b1, acc[0][1], 0, 0, 0);
            acc[1][0] = __builtin_amdgcn_mfma_f32_16x16x32_bf16(a1, b0, acc[1][0], 0, 0, 0);
            acc[1][1] = __builtin_amdgcn_mfma_f32_16x16x32_bf16(a1, b1, acc[1][1], 0, 0, 0);
        }
    }

#pragma unroll
    for (int m = 0; m < 2; ++m)
#pragma unroll
        for (int n = 0; n < 2; ++n)
#pragma unroll
            for (int r = 0; r < 4; ++r) {
                const int grow = i0 + mr0 + 16 * m + 4 * lhi + r;
                const int gcol = j0 + nc0 + 16 * n + l15;
                C[(size_t)grow * 512 + gcol] = acc[m][n][r] + bias[gcol];
            }
}

// ===========================================================================
// Fused score + softmax + PV, QBLK=16 rows/block (R15 structure — best).
// Main loop barrier-free with PER-WAVE self-staging; K and P time-share one
// staging buffer Sb (wave-private rows; in-wave DS ordering handles hazard).
// launch_bounds(512,4): VGPR cap 128 (no spills).
// First-half V loads issued before the softmax epilogue (T14 split).
// R is stored PRE-SHIFTED (scatter): R[gr,u] -> Rsh[rl][u+gr-1023] if
// u>=1023-gr, else Rsh[rl-1][u+gr+1]; slot j=i+1 pre-zeroed.
// ===========================================================================
#define RS 1032   // padded LDS row stride (shorts)
#define QBLK 16

__global__ __launch_bounds__(512, 4) void score_fused_k(
    const unsigned short* __restrict__ qu_g,  // [B,H,S,DH]
    const unsigned short* __restrict__ qv_g,
    const unsigned short* __restrict__ kb_g,
    const unsigned short* __restrict__ pb_g,
    const unsigned short* __restrict__ v2_g,  // blocked [BH][32][64][32]
    float* __restrict__ attn,                 // [B,H,S,S]
    unsigned short* __restrict__ ctx_g)       // [B,S,D] bf16
{
    __shared__ unsigned short Sb[128][72];    // K/P time-shared; PV partials alias
    __shared__ unsigned short Rsh[16 * RS];   // shifted R, then P  (33 KB)
    __shared__ float red[16][9];

    const int tid = threadIdx.x;
    const int i0 = blockIdx.x * QBLK;
    const int bh = blockIdx.y;
    const int w = tid >> 6, lane = tid & 63, l15 = lane & 15, lhi = lane >> 4;

    const unsigned short* qu_b = qu_g + (size_t)bh * S_ * DH_;
    const unsigned short* qv_b = qv_g + (size_t)bh * S_ * DH_;
    const unsigned short* kb_b = kb_g + (size_t)bh * S_ * DH_;
    const unsigned short* pb_b = pb_g + (size_t)bh * S_ * DH_;

    // ---- zero the j = i+1 slots of Rsh (one per row) ----
    if (tid < 16) {
        const int j = i0 + tid + 1;
        if (j <= 1023) Rsh[tid * RS + j] = 0;
    }

    // ---- A-operand fragments in registers ----
    bf16x8 qf[2], aq0[2], aq1[2];
    {
        const int qrow  = i0 + l15;
        const int qrow1 = min(i0 + 16 + l15, S_ - 1);
#pragma unroll
        for (int kk = 0; kk < 2; ++kk) {
            const int off = kk * 32 + lhi * 8;
            qf[kk]  = *(const bf16x8*)&qu_b[(size_t)qrow  * DH_ + off];
            aq0[kk] = *(const bf16x8*)&qv_b[(size_t)qrow  * DH_ + off];
            aq1[kk] = *(const bf16x8*)&qv_b[(size_t)qrow1 * DH_ + off];
        }
    }

    // ---- main loop: 8 chunks of 128 cols; wave-private staging, 0 barriers.
    const int srow0 = 16 * w + (lane >> 3);       // +8 for it=1
    const int sseg  = (lane & 7) * 8;

    bf16x8 kreg[2], preg[2];
#pragma unroll
    for (int it = 0; it < 2; ++it) {       // prologue: load chunk 0
        const size_t g = (size_t)(srow0 + it * 8) * DH_ + sseg;
        kreg[it] = *(const bf16x8*)&kb_b[g];
        preg[it] = *(const bf16x8*)&pb_b[g];
    }

    f32x4 acc[8] = {};
#pragma unroll
    for (int jc = 0; jc < 8; ++jc) {
        // -- stage K chunk jc (wave-private rows), prefetch next K --
#pragma unroll
        for (int it = 0; it < 2; ++it)
            *(bf16x8*)&Sb[srow0 + it * 8][sseg] = kreg[it];
        if (jc < 7) {
#pragma unroll
            for (int it = 0; it < 2; ++it) {
                const size_t g = (size_t)((jc + 1) * 128 + srow0 + it * 8) * DH_ + sseg;
                kreg[it] = *(const bf16x8*)&kb_b[g];
            }
        }
        // -- content MFMA from Sb (K) --
        {
            bf16x8 kf0 = *(const bf16x8*)&Sb[16 * w + l15][lhi * 8];
            bf16x8 kf1 = *(const bf16x8*)&Sb[16 * w + l15][32 + lhi * 8];
            acc[jc] = __builtin_amdgcn_mfma_f32_16x16x32_bf16(qf[0], kf0, acc[jc], 0, 0, 0);
            acc[jc] = __builtin_amdgcn_mfma_f32_16x16x32_bf16(qf[1], kf1, acc[jc], 0, 0, 0);
        }
        // -- stage P chunk jc into the SAME buffer, prefetch next P --
#pragma unroll
        for (int it = 0; it < 2; ++it)
            *(bf16x8*)&Sb[srow0 + it * 8][sseg] = preg[it];
        if (jc < 7) {
#pragma unroll
            for (int it = 0; it < 2; ++it) {
                const size_t g = (size_t)((jc + 1) * 128 + srow0 + it * 8) * DH_ + sseg;
                preg[it] = *(const bf16x8*)&pb_b[g];
            }
        }
        // -- pos MFMA from Sb (P) --
        f32x4 racc0 = {}, racc1 = {};
        {
            bf16x8 pf0 = *(const bf16x8*)&Sb[16 * w + l15][lhi * 8];
            bf16x8 pf1 = *(const bf16x8*)&Sb[16 * w + l15][32 + lhi * 8];
            racc0 = __builtin_amdgcn_mfma_f32_16x16x32_bf16(aq0[0], pf0, racc0, 0, 0, 0);
            racc0 = __builtin_amdgcn_mfma_f32_16x16x32_bf16(aq0[1], pf1, racc0, 0, 0, 0);
            racc1 = __builtin_amdgcn_mfma_f32_16x16x32_bf16(aq1[0], pf0, racc1, 0, 0, 0);
            racc1 = __builtin_amdgcn_mfma_f32_16x16x32_bf16(aq1[1], pf1, racc1, 0, 0, 0);
        }

        // -- scatter-store R pre-shifted --
        const int u = jc * 128 + 16 * w + l15;
#pragma unroll
        for (int r = 0; r < 4; ++r) {
            const int rl = 4 * lhi + r;          // R local row 0..15
            const int gr = i0 + rl;
            const int jlo = u + gr - 1023;
            const unsigned short val = f2bf(racc0[r]);
            if (jlo >= 0)      Rsh[rl * RS + jlo] = val;
            else if (rl >= 1)  Rsh[(rl - 1) * RS + (u + gr + 1)] = val;
            // rl==0 && jlo<0: previous strip's territory -> drop
        }
        if (lhi == 0) {                          // R local row 16 (racc1[0])
            const int jhi = u + i0 + 17;
            if (jhi <= 1023) Rsh[15 * RS + jhi] = f2bf(racc1[0]);
        }
    }
    __syncthreads();                       // Rsh (shifted R) complete

    // ---- T14: issue first-half V loads now; latency hides under softmax ----
    const int b4 = bh >> 3, h4 = bh & 7;
    const int nblk = w & 3;                // d-block (16 cols)
    const int kh = w >> 2;                 // K-half (512 each)
    const unsigned short* v2b = v2_g + (size_t)bh * 32 * 2048;
    const int dd = 16 * nblk + l15;
    bf16x8 bbufA[8];
#pragma unroll
    for (int ki = 0; ki < 8; ++ki) {
        const int tb = kh * 16 + ki;
        bbufA[ki] = *(const bf16x8*)&v2b[(size_t)tb * 2048 + dd * 32 + lhi * 8];
    }

    // ---- epilogue: branch-free pos add + scale + softmax ----
    const int il = 4 * lhi;                // + r
    float rmax[4], rsum[4];
#pragma unroll
    for (int r = 0; r < 4; ++r) rmax[r] = -3.0e38f;

#pragma unroll
    for (int jc = 0; jc < 8; ++jc)
#pragma unroll
        for (int r = 0; r < 4; ++r) {
            const int row = il + r;
            const int j = jc * 128 + 16 * w + l15;
            const float pos = bf2f(Rsh[row * RS + j]);
            const float s = (acc[jc][r] + pos) * SCALE;
            acc[jc][r] = s;
            rmax[r] = fmaxf(rmax[r], s);
        }

#pragma unroll
    for (int r = 0; r < 4; ++r)
#pragma unroll
        for (int off = 1; off < 16; off <<= 1)
            rmax[r] = fmaxf(rmax[r], __shfl_xor(rmax[r], off));
    if (l15 == 0)
#pragma unroll
        for (int r = 0; r < 4; ++r) red[il + r][w] = rmax[r];
    __syncthreads();
#pragma unroll
    for (int r = 0; r < 4; ++r) {
        float mx = red[il + r][0];
#pragma unroll
        for (int ww = 1; ww < 8; ++ww) mx = fmaxf(mx, red[il + r][ww]);
        rmax[r] = mx;
        rsum[r] = 0.f;
    }
    __syncthreads();                       // red reads done before reuse

#pragma unroll
    for (int jc = 0; jc < 8; ++jc)
#pragma unroll
        for (int r = 0; r < 4; ++r) {
            const float e = __expf(acc[jc][r] - rmax[r]);
            acc[jc][r] = e;
            rsum[r] += e;
        }
#pragma unroll
    for (int r = 0; r < 4; ++r)
#pragma unroll
        for (int off = 1; off < 16; off <<= 1)
            rsum[r] += __shfl_xor(rsum[r], off);
    if (l15 == 0)
#pragma unroll
        for (int r = 0; r < 4; ++r) red[il + r][w] = rsum[r];
    __syncthreads();

    // ---- normalize: write attn (fp32) + P (bf16, overwrites Rsh) ----
    float* attn_b = attn + (size_t)bh * S_ * S_;
#pragma unroll
    for (int r = 0; r < 4; ++r) {
        float sum = red[il + r][0];
#pragma unroll
        for (int ww = 1; ww < 8; ++ww) sum += red[il + r][ww];
        const float inv = 1.f / sum;
#pragma unroll
        for (int jc = 0; jc < 8; ++jc) {
            const int j = jc * 128 + 16 * w + l15;
            const float pn = acc[jc][r] * inv;
            attn_b[(size_t)(i0 + il + r) * S_ + j] = pn;
            Rsh[(il + r) * RS + j] = f2bf(pn);
        }
    }
    __syncthreads();                       // P complete in LDS

    // ---- fused PV: ctx[i0..i0+16, h*64..] = P @ V ----
    bf16x8 bbufB[8];
#pragma unroll
    for (int ki = 0; ki < 8; ++ki) {
        const int tb = kh * 16 + 8 + ki;
        bbufB[ki] = *(const bf16x8*)&v2b[(size_t)tb * 2048 + dd * 32 + lhi * 8];
    }
    f32x4 cacc = {};
#pragma unroll
    for (int ki = 0; ki < 8; ++ki) {
        const int t0 = (kh * 16 + ki) * 32 + lhi * 8;
        bf16x8 a = *(const bf16x8*)&Rsh[l15 * RS + t0];
        cacc = __builtin_amdgcn_mfma_f32_16x16x32_bf16(a, bbufA[ki], cacc, 0, 0, 0);
    }
#pragma unroll
    for (int ki = 0; ki < 8; ++ki) {
        const int t0 = (kh * 16 + 8 + ki) * 32 + lhi * 8;
        bf16x8 a = *(const bf16x8*)&Rsh[l15 * RS + t0];
        cacc = __builtin_amdgcn_mfma_f32_16x16x32_bf16(a, bbufB[ki], cacc, 0, 0, 0);
    }
    float* fred = (float*)&Sb[0][0];       // PV partials (Sb dead, 4 KB)
    if (kh == 0) {
#pragma unroll
        for (int r = 0; r < 4; ++r)
            fred[(nblk * 16 + 4 * lhi + r) * 16 + l15] = cacc[r];
    }
    __syncthreads();
    if (kh == 1) {
#pragma unroll
        for (int r = 0; r < 4; ++r) {
            const float vs = cacc[r] + fred[(nblk * 16 + 4 * lhi + r) * 16 + l15];
            const int srow = i0 + 4 * lhi + r;
            ctx_g[((size_t)(b4 * S_ + srow)) * D_ + h4 * DH_ + 16 * nblk + l15] = f2bf(vs);
        }
    }
}

// ===========================================================================
extern "C" void kernel_launch(void* const* d_in, const int* in_sizes, int n_in,
                              void* d_out, int out_size, void* d_ws, size_t ws_size,
                              hipStream_t stream)
{
    const float* query = (const float*)d_in[0];
    const float* key_  = (const float*)d_in[1];
    const float* value = (const float*)d_in[2];
    const float* pose  = (const float*)d_in[3];
    const float* Wq = (const float*)d_in[4];
    const float* bq = (const float*)d_in[5];
    const float* Wk = (const float*)d_in[6];
    const float* bk = (const float*)d_in[7];
    const float* Wv = (const float*)d_in[8];
    const float* bv = (const float*)d_in[9];
    const float* Wp = (const float*)d_in[10];
    const float* Wo = (const float*)d_in[11];
    const float* bo = (const float*)d_in[12];
    const float* u_bias = (const float*)d_in[13];
    const float* v_bias = (const float*)d_in[14];

    const size_t NTOK = (size_t)B_ * S_ * D_;   // 2,097,152
    float* out  = (float*)d_out;                // [B,S,D]
    float* attn = (float*)d_out + NTOK;         // [B,H,S,S]

    unsigned short* qu  = (unsigned short*)d_ws;
    unsigned short* qv  = qu + NTOK;
    unsigned short* kbf = qv + NTOK;
    unsigned short* pbf = kbf + NTOK;
    unsigned short* WqT = pbf + NTOK;
    unsigned short* WkT = WqT + 262144;
    unsigned short* WpT = WkT + 262144;
    unsigned short* WvT = WpT + 262144;
    unsigned short* WoT = WvT + 262144;
    unsigned short* v2  = WoT + 262144;         // blocked V bf16
    unsigned short* ctx = v2 + NTOK;            // [B,S,D] bf16

    const dim3 blk256(256);
    const dim3 gproj(64, 8);

    convert_wt_k<<<dim3(8, 8, 5), blk256, 0, stream>>>(Wq, Wk, Wp, Wv, Wo,
                                                       WqT, WkT, WpT, WvT, WoT);

    proj_all_k<<<dim3(32, 4, 4), dim3(512), 0, stream>>>(
        query, key_, pose, value,
        WqT, WkT, WpT, WvT,
        bq, bk, bv, u_bias, v_bias,
        qu, qv, kbf, pbf, v2);

    score_fused_k<<<dim3(S_ / QBLK, B_ * H_), dim3(512), 0, stream>>>(
        qu, qv, kbf, pbf, v2, attn, ctx);

    gemm_bf16_k<<<gproj, blk256, 0, stream>>>(ctx, WoT, bo, out);
}